// Round 10
// baseline (805.984 us; speedup 1.0000x reference)
//
#include <hip/hip_runtime.h>
#include <stdint.h>

#define HID 512
#define THREE_H 1536
#define ADIM 256
#define NVOC 10000
#define TEnc 256
#define TDec 128

typedef float f32x4 __attribute__((ext_vector_type(4)));
typedef __bf16 bf16x8 __attribute__((ext_vector_type(8)));

__device__ __forceinline__ unsigned short f2bf(float f) {
  union { float f; unsigned u; } v; v.f = f;
  unsigned r = v.u + 0x7FFFu + ((v.u >> 16) & 1u);
  return (unsigned short)(r >> 16);
}
__device__ __forceinline__ float sigmoidf_(float x) { return 1.f / (1.f + __expf(-x)); }
__device__ __forceinline__ float tanh_fast(float x) {
  float ax = fabsf(x);
  float e = __expf(ax + ax);
  float t = 1.f - 2.f / (e + 1.f);
  return copysignf(t, x);
}

// Exchange primitives.
// MEASURED (r6-r9): sys-scope (sc0 sc1) store->remote-visibility RTT ~2.8us/hop,
// invariant to line-spreading (r8), poller rate (r9); store count matters (r7).
// NEW BET (r10): no-sc1 ATOMICS execute at the issuing XCD's L2 (atomics are
// never L1-satisfied -- r4's stale-L1 load failure doesn't apply). With all
// workers election-pinned to ONE XCD, producer atomic_swap + consumer
// atomic_or-read meet in the same L2 (~300cy). Sys-scope mirror = fallback.
__device__ __forceinline__ void st_u64_sys(unsigned long long* p, unsigned long long v) {
  asm volatile("global_store_dwordx2 %0, %1, off sc0 sc1" :: "v"(p), "v"(v) : "memory");
}
__device__ __forceinline__ void ld2_u64_sys(const unsigned long long* p0,
                                            const unsigned long long* p1,
                                            unsigned long long& a, unsigned long long& b) {
  asm volatile("global_load_dwordx2 %0, %2, off sc0 sc1\n\t"
               "global_load_dwordx2 %1, %3, off sc0 sc1\n\t"
               "s_waitcnt vmcnt(0)"
               : "=&v"(a), "=&v"(b)
               : "v"(p0), "v"(p1)
               : "memory");
}
__device__ __forceinline__ void at_swap_l2(unsigned* p, unsigned v) {
  asm volatile("global_atomic_swap %0, %1, off" :: "v"(p), "v"(v) : "memory");
}
__device__ __forceinline__ void at_or4_l2(const unsigned* p0, const unsigned* p1,
                                          const unsigned* p2, const unsigned* p3,
                                          unsigned& a, unsigned& b, unsigned& c, unsigned& d) {
  unsigned z = 0;
  asm volatile("global_atomic_or %0, %4, %8, off sc0\n\t"
               "global_atomic_or %1, %5, %8, off sc0\n\t"
               "global_atomic_or %2, %6, %8, off sc0\n\t"
               "global_atomic_or %3, %7, %8, off sc0\n\t"
               "s_waitcnt vmcnt(0)"
               : "=&v"(a), "=&v"(b), "=&v"(c), "=&v"(d)
               : "v"(p0), "v"(p1), "v"(p2), "v"(p3), "v"(z)
               : "memory");
}

#define GLDS16(gp, lp)                                                                 \
  __builtin_amdgcn_global_load_lds((const __attribute__((address_space(1))) void*)(gp),\
                                   (__attribute__((address_space(3))) void*)(lp), 16, 0, 0)

// ---------------- fp32 -> bf16 convert (x and y fused) ----------------
__global__ void cvt_xy(const float* __restrict__ x, const float* __restrict__ y,
                       unsigned short* __restrict__ xb, unsigned short* __restrict__ yb) {
  int i = (blockIdx.x * blockDim.x + threadIdx.x) * 4;
  const float* src;
  unsigned short* dst;
  int j;
  if (i < TEnc * HID) { src = x; dst = xb; j = i; }
  else { src = y; dst = yb; j = i - TEnc * HID; }
  float4 v = *(const float4*)(src + j);
  ushort4 o;
  o.x = f2bf(v.x); o.y = f2bf(v.y); o.z = f2bf(v.z); o.w = f2bf(v.w);
  *(ushort4*)(dst + j) = o;
}

// ---------------- BT-GEMM: C[M,N] = A[M,K](bf16) * B[N,K]^T(f32->bf16) + bias ----------------
template <int BN, int BK>
__global__ __launch_bounds__(256, 1) void gemm_bt(
    const unsigned short* __restrict__ Abf, const float* __restrict__ B,
    const float* __restrict__ bias, float* __restrict__ C, unsigned short* __restrict__ Cbf,
    int M, int N, int K) {
  constexpr int NF = BN / 16;
  constexpr int B4 = BN * BK / 1024;
  constexpr int AG = BK / 16;
  constexpr int KK = BK / 32;
  extern __shared__ char smem[];
  unsigned short* Al0 = (unsigned short*)smem;
  unsigned short* Al1 = Al0 + 128 * BK;
  unsigned short* Bl0 = Al1 + 128 * BK;
  unsigned short* Bl1 = Bl0 + BN * BK;

  const int tid = threadIdx.x;
  const int lane = tid & 63;
  const int wid = tid >> 6;
  const int m0 = blockIdx.x * 128;
  const int n0 = blockIdx.y * BN;
  const int NT = K / BK;

  float4 breg[B4];
  f32x4 acc[2][NF];
#pragma unroll
  for (int i = 0; i < 2; ++i)
#pragma unroll
    for (int j = 0; j < NF; ++j) acc[i][j] = (f32x4){0.f, 0.f, 0.f, 0.f};

  auto stageA = [&](int t, unsigned short* dst) {
    const unsigned short* Ab = Abf + (size_t)m0 * K + (size_t)t * BK;
#pragma unroll
    for (int g = 0; g < AG; ++g) {
      int elem = g * 2048 + tid * 8;
      int arow = elem / BK;
      int acol = elem - arow * BK;
      GLDS16(Ab + (size_t)arow * K + acol, (char*)dst + g * 4096 + wid * 1024);
    }
  };
  auto loadB = [&](int t) {
    const float* Bb = B + (size_t)t * BK;
#pragma unroll
    for (int p = 0; p < B4; ++p) {
      int e = (p * 256 + tid) * 4;
      int brow = e / BK;
      int bcol = e - brow * BK;
      int grow = n0 + brow;
      if (grow > N - 1) grow = N - 1;
      breg[p] = *(const float4*)(Bb + (size_t)grow * K + bcol);
    }
  };
  auto writeB = [&](unsigned short* dst) {
#pragma unroll
    for (int p = 0; p < B4; ++p) {
      ushort4 o;
      o.x = f2bf(breg[p].x); o.y = f2bf(breg[p].y);
      o.z = f2bf(breg[p].z); o.w = f2bf(breg[p].w);
      *(ushort4*)((char*)dst + (p * 256 + tid) * 8) = o;
    }
  };

  stageA(0, Al0);
  loadB(0);
  for (int t = 0; t < NT; ++t) {
    unsigned short* Ac = (t & 1) ? Al1 : Al0;
    unsigned short* Bc = (t & 1) ? Bl1 : Bl0;
    asm volatile("s_waitcnt vmcnt(0)" ::: "memory");
    writeB(Bc);
    __syncthreads();
    if (t + 1 < NT) {
      stageA(t + 1, (t & 1) ? Al0 : Al1);
      loadB(t + 1);
    }
    const int r0 = lane & 15;
    const int kb = (lane >> 4) * 8;
#pragma unroll
    for (int kk = 0; kk < KK; ++kk) {
      int ko = kk * 32 + kb;
      bf16x8 a0 = *(const bf16x8*)(Ac + (wid * 32 + r0) * BK + ko);
      bf16x8 a1 = *(const bf16x8*)(Ac + (wid * 32 + 16 + r0) * BK + ko);
#pragma unroll
      for (int nf = 0; nf < NF; ++nf) {
        bf16x8 bb = *(const bf16x8*)(Bc + (nf * 16 + r0) * BK + ko);
        acc[0][nf] = __builtin_amdgcn_mfma_f32_16x16x32_bf16(a0, bb, acc[0][nf], 0, 0, 0);
        acc[1][nf] = __builtin_amdgcn_mfma_f32_16x16x32_bf16(a1, bb, acc[1][nf], 0, 0, 0);
      }
    }
  }
  const int cc = lane & 15;
  const int rq = (lane >> 4) * 4;
#pragma unroll
  for (int mi = 0; mi < 2; ++mi) {
    int row = m0 + wid * 32 + mi * 16 + rq;
#pragma unroll
    for (int nf = 0; nf < NF; ++nf) {
      int col = n0 + nf * 16 + cc;
      if (col < N) {
        float bv = bias ? bias[col] : 0.f;
#pragma unroll
        for (int j = 0; j < 4; ++j) {
          float v = acc[mi][nf][j] + bv;
          if (C) C[(size_t)(row + j) * N + col] = v;
          if (Cbf) Cbf[(size_t)(row + j) * N + col] = f2bf(v);
        }
      }
    }
  }
}

// ---------------- encoder GEMM with fused GRU gates (h_prev = 0) ----------------
__global__ __launch_bounds__(256, 1) void gemm_enc(
    const unsigned short* __restrict__ Abf, const float* __restrict__ Wi,
    const float* __restrict__ bi, const float* __restrict__ bh,
    float* __restrict__ encH, unsigned short* __restrict__ encHbf) {
  constexpr int BN = 96, BK = 128, NF = 6, B4 = 12, AG = 8, KK = 4, K = 512;
  extern __shared__ char smem[];
  unsigned short* Al0 = (unsigned short*)smem;
  unsigned short* Al1 = Al0 + 128 * BK;
  unsigned short* Bl0 = Al1 + 128 * BK;
  unsigned short* Bl1 = Bl0 + BN * BK;

  const int tid = threadIdx.x;
  const int lane = tid & 63;
  const int wid = tid >> 6;
  const int m0 = blockIdx.x * 128;
  const int n0g = blockIdx.y * 32;
  const int NT = K / BK;

  float4 breg[B4];
  f32x4 acc[2][NF];
#pragma unroll
  for (int i = 0; i < 2; ++i)
#pragma unroll
    for (int j = 0; j < NF; ++j) acc[i][j] = (f32x4){0.f, 0.f, 0.f, 0.f};

  auto stageA = [&](int t, unsigned short* dst) {
    const unsigned short* Ab = Abf + (size_t)m0 * K + (size_t)t * BK;
#pragma unroll
    for (int g = 0; g < AG; ++g) {
      int elem = g * 2048 + tid * 8;
      int arow = elem >> 7;
      int acol = elem & 127;
      GLDS16(Ab + (size_t)arow * K + acol, (char*)dst + g * 4096 + wid * 1024);
    }
  };
  auto loadB = [&](int t) {
    const float* Bb = Wi + (size_t)t * BK;
#pragma unroll
    for (int p = 0; p < B4; ++p) {
      int e = (p * 256 + tid) * 4;
      int brow = e >> 7;
      int bcol = e & 127;
      int grow = (brow >> 5) * HID + n0g + (brow & 31);
      breg[p] = *(const float4*)(Bb + (size_t)grow * K + bcol);
    }
  };
  auto writeB = [&](unsigned short* dst) {
#pragma unroll
    for (int p = 0; p < B4; ++p) {
      ushort4 o;
      o.x = f2bf(breg[p].x); o.y = f2bf(breg[p].y);
      o.z = f2bf(breg[p].z); o.w = f2bf(breg[p].w);
      *(ushort4*)((char*)dst + (p * 256 + tid) * 8) = o;
    }
  };

  stageA(0, Al0);
  loadB(0);
  for (int t = 0; t < NT; ++t) {
    unsigned short* Ac = (t & 1) ? Al1 : Al0;
    unsigned short* Bc = (t & 1) ? Bl1 : Bl0;
    asm volatile("s_waitcnt vmcnt(0)" ::: "memory");
    writeB(Bc);
    __syncthreads();
    if (t + 1 < NT) {
      stageA(t + 1, (t & 1) ? Al0 : Al1);
      loadB(t + 1);
    }
    const int r0 = lane & 15;
    const int kb = (lane >> 4) * 8;
#pragma unroll
    for (int kk = 0; kk < KK; ++kk) {
      int ko = kk * 32 + kb;
      bf16x8 a0 = *(const bf16x8*)(Ac + (wid * 32 + r0) * BK + ko);
      bf16x8 a1 = *(const bf16x8*)(Ac + (wid * 32 + 16 + r0) * BK + ko);
#pragma unroll
      for (int nf = 0; nf < NF; ++nf) {
        bf16x8 bb = *(const bf16x8*)(Bc + (nf * 16 + r0) * BK + ko);
        acc[0][nf] = __builtin_amdgcn_mfma_f32_16x16x32_bf16(a0, bb, acc[0][nf], 0, 0, 0);
        acc[1][nf] = __builtin_amdgcn_mfma_f32_16x16x32_bf16(a1, bb, acc[1][nf], 0, 0, 0);
      }
    }
  }
  const int cc = lane & 15;
  const int rq = (lane >> 4) * 4;
#pragma unroll
  for (int mi = 0; mi < 2; ++mi) {
    int row = m0 + wid * 32 + mi * 16 + rq;
#pragma unroll
    for (int nfj = 0; nfj < 2; ++nfj) {
      int j = n0g + nfj * 16 + cc;
      float br_ = bi[j] + bh[j];
      float bz_ = bi[HID + j] + bh[HID + j];
      float bin_ = bi[2 * HID + j];
      float bhn_ = bh[2 * HID + j];
#pragma unroll
      for (int jj = 0; jj < 4; ++jj) {
        float r = sigmoidf_(acc[mi][nfj][jj] + br_);
        float z = sigmoidf_(acc[mi][nfj + 2][jj] + bz_);
        float n = tanh_fast(acc[mi][nfj + 4][jj] + bin_ + r * bhn_);
        float h = (1.f - z) * n;
        encH[(size_t)(row + jj) * HID + j] = h;
        encHbf[(size_t)(row + jj) * HID + j] = f2bf(h);
      }
    }
  }
}

// ---------------- sequential GRU scan: single-XCD cluster, L2-atomic exchange ----------------
// 256 WGs (1/CU via 100KB LDS); winner XCD's 32 WGs work (r2/r3-proven election).
// Exchange per step: producer publishes each dim as u32 (tag16|bf16) via
// no-sc1 global_atomic_swap (lands in winner XCD's L2) AND mirrors r6's
// sys-scope u64 packing. Consumers (waves 0-1, 4 dims/lane) poll via
// global_atomic_or-0 (returns old, L2-serviced; never stale-L1) for 8
// bounded rounds, then fall back to the PROVEN sys-scope mirror. Mailbox
// words line-padded (128B). Own-dim recurrence fp32 in wave3's hreg.
__global__ __launch_bounds__(256, 1) void gru_scan_xcd(
    const float* __restrict__ Whd, const float* __restrict__ bhd,
    const float* __restrict__ giY, const float* __restrict__ h0,
    unsigned* __restrict__ hxA, unsigned long long* __restrict__ hxS,
    unsigned* __restrict__ cnt, unsigned* __restrict__ winner,
    unsigned short* __restrict__ decSbf, unsigned short* __restrict__ concatbf) {
  extern __shared__ char smem[];
  float* hl = (float*)smem;        // 548 floats; word w -> slot w + ((w>>7)<<2)
  float* dots = hl + 548;          // 48
  volatile int* slot_sh = (volatile int*)(dots + 48);
  const int tid = threadIdx.x;
  const int lane = tid & 63, wid = tid >> 6;

  // ---- election (r2/r3-proven) ----
  if (tid == 0) {
    unsigned xcd;
    asm volatile("s_getreg_b32 %0, hwreg(20, 0, 32)" : "=s"(xcd));
    xcd &= 7u;
    unsigned slot = atomicAdd(&cnt[xcd], 1u);
    if (slot == 31u) atomicCAS(winner, 0u, xcd + 1u);
    unsigned win = 0;
    if (slot < 32u) {
      int spin = 0;
      while ((win = __hip_atomic_load(winner, __ATOMIC_RELAXED,
                                      __HIP_MEMORY_SCOPE_AGENT)) == 0u &&
             ++spin < (1 << 20))
        __builtin_amdgcn_s_sleep(2);
    }
    *slot_sh = (slot < 32u && win == xcd + 1u) ? (int)slot : -1;
  }
  __syncthreads();
  const int g = *slot_sh;
  if (g < 0) return;

  const int row16 = lane & 15;
  const int q = lane >> 4;
  float4 wreg[32];
  {
    int wrow = (wid < 3) ? wid : 0;
    const float* wr = Whd + ((size_t)wrow * HID + (size_t)g * 16 + row16) * HID + q * 128;
#pragma unroll
    for (int i = 0; i < 32; ++i) wreg[i] = *(const float4*)(wr + i * 4);
  }
  float bhr = 0.f, bhz = 0.f, bhn = 0.f, hreg = 0.f;
  if (wid == 3 && lane < 16) {
    int jj = g * 16 + lane;
    bhr = bhd[jj]; bhz = bhd[HID + jj]; bhn = bhd[2 * HID + jj];
    hreg = h0[jj];
  }
  {
    int w0 = tid * 2, w1 = tid * 2 + 1;
    hl[w0 + ((w0 >> 7) << 2)] = h0[w0];
    hl[w1 + ((w1 >> 7) << 2)] = h0[w1];
  }
  __syncthreads();

  for (int t = 0; t < TDec; ++t) {
    float gir = 0.f, giz = 0.f, gin = 0.f;
    if (wid < 3) {
      const float4* hp = (const float4*)hl;
      const int hb = q * 33;
      float p0 = 0.f, p1 = 0.f, p2 = 0.f, p3 = 0.f;
#pragma unroll
      for (int i = 0; i < 32; i += 4) {
        float4 ha = hp[hb + i], hv = hp[hb + i + 1], hc = hp[hb + i + 2], hd = hp[hb + i + 3];
        float4 wa = wreg[i], wb = wreg[i + 1], wc = wreg[i + 2], wd = wreg[i + 3];
        p0 += wa.x * ha.x + wa.y * ha.y + wa.z * ha.z + wa.w * ha.w;
        p1 += wb.x * hv.x + wb.y * hv.y + wb.z * hv.z + wb.w * hv.w;
        p2 += wc.x * hc.x + wc.y * hc.y + wc.z * hc.z + wc.w * hc.w;
        p3 += wd.x * hd.x + wd.y * hd.y + wd.z * hd.z + wd.w * hd.w;
      }
      float p = (p0 + p1) + (p2 + p3);
      p += __shfl_xor(p, 16);
      p += __shfl_xor(p, 32);
      if (lane < 16) dots[wid * 16 + lane] = p;
    } else if (lane < 16) {
      int jj = g * 16 + lane;
      const float* gi = giY + (size_t)t * THREE_H;
      gir = gi[jj]; giz = gi[HID + jj]; gin = gi[2 * HID + jj];  // hidden under dots
    }
    __syncthreads();  // dots ready; hl(t) reads done
    const unsigned tagv = (unsigned)(t + 1);
    unsigned* hxAB = hxA + (size_t)(t & 1) * 512 * 32;
    unsigned long long* hxSB = hxS + (size_t)(t & 1) * 256;
    if (wid == 3 && lane < 16) {
      int jj = g * 16 + lane;
      float r = sigmoidf_(gir + dots[lane] + bhr);
      float z = sigmoidf_(giz + dots[16 + lane] + bhz);
      float n = tanh_fast(gin + r * (dots[32 + lane] + bhn));
      float hn = (1.f - z) * n + z * hreg;
      hreg = hn;
      unsigned short hb16 = f2bf(hn);
      // L2-atomic publish: one tagged u32 per dim, own 128B line
      at_swap_l2(hxAB + (unsigned)jj * 32, (tagv << 16) | (unsigned)hb16);
      // sys-scope mirror (r6 packing) for the fallback path
      unsigned short hb_up = (unsigned short)__shfl_xor((int)hb16, 1);
      if ((lane & 1) == 0) {
        unsigned long long w = ((unsigned long long)tagv << 32) |
                               ((unsigned)hb_up << 16) | (unsigned)hb16;
        st_u64_sys(hxSB + g * 8 + (lane >> 1), w);
      }
      decSbf[(size_t)t * HID + jj] = hb16;
      concatbf[(size_t)t * 2 * HID + HID + jj] = hb16;
    }
    if (t == TDec - 1) break;
    if (tid < 128) {
      // fast path: L2-atomic poll, 4 dims/lane, 8 bounded rounds
      const unsigned* a0 = hxAB + (tid * 4 + 0) * 32;
      const unsigned* a1 = hxAB + (tid * 4 + 1) * 32;
      const unsigned* a2 = hxAB + (tid * 4 + 2) * 32;
      const unsigned* a3 = hxAB + (tid * 4 + 3) * 32;
      unsigned rr0 = 0, rr1 = 0, rr2 = 0, rr3 = 0, have = 0;
      __builtin_amdgcn_s_sleep(1);
      for (int rd = 0; rd < 8 && have != 0xFu; ++rd) {
        unsigned v0, v1, v2, v3;
        at_or4_l2(a0, a1, a2, a3, v0, v1, v2, v3);
        if (!(have & 1u) && (v0 >> 16) == tagv) { rr0 = v0 & 0xFFFFu; have |= 1u; }
        if (!(have & 2u) && (v1 >> 16) == tagv) { rr1 = v1 & 0xFFFFu; have |= 2u; }
        if (!(have & 4u) && (v2 >> 16) == tagv) { rr2 = v2 & 0xFFFFu; have |= 4u; }
        if (!(have & 8u) && (v3 >> 16) == tagv) { rr3 = v3 & 0xFFFFu; have |= 8u; }
        if (have != 0xFu) __builtin_amdgcn_s_sleep(1);
      }
      if (have != 0xFu) {
        // fallback: PROVEN sys-scope mirror poll (r6 path)
        const unsigned long long* s0 = hxSB + tid * 2;
        const unsigned long long* s1 = s0 + 1;
        unsigned long long w0 = 0, w1 = 0;
        bool k0 = false, k1 = false;
        int gd = 0;
        while ((!k0 || !k1) && ++gd < (1 << 20)) {
          unsigned long long xv, yv;
          ld2_u64_sys(s0, s1, xv, yv);
          if ((unsigned)(xv >> 32) == tagv) { w0 = xv; k0 = true; }
          if ((unsigned)(yv >> 32) == tagv) { w1 = yv; k1 = true; }
        }
        rr0 = (unsigned)w0 & 0xFFFFu;
        rr1 = ((unsigned)w0 >> 16) & 0xFFFFu;
        rr2 = (unsigned)w1 & 0xFFFFu;
        rr3 = ((unsigned)w1 >> 16) & 0xFFFFu;
      }
      int d0 = tid * 4, d1 = d0 + 1, d2 = d0 + 2, d3 = d0 + 3;
      hl[d0 + ((d0 >> 7) << 2)] = __uint_as_float(rr0 << 16);
      hl[d1 + ((d1 >> 7) << 2)] = __uint_as_float(rr1 << 16);
      hl[d2 + ((d2 >> 7) << 2)] = __uint_as_float(rr2 << 16);
      hl[d3 + ((d3 >> 7) << 2)] = __uint_as_float(rr3 << 16);
    }
    __syncthreads();  // hl(t+1) ready
  }
}

// ---------------- attention scores + softmax + context ----------------
__global__ __launch_bounds__(256) void attn_ctx(const float* __restrict__ encP,
                                                const float* __restrict__ decP,
                                                const float* __restrict__ vattn,
                                                const float* __restrict__ encH,
                                                unsigned short* __restrict__ concatbf) {
  __shared__ float dp[ADIM], vv[ADIM], pl[TEnc];
  __shared__ float red[8];
  const int t = blockIdx.x, tid = threadIdx.x;
  if (tid < 64) {
    *(float4*)(dp + tid * 4) = *(const float4*)(decP + (size_t)t * ADIM + tid * 4);
    *(float4*)(vv + tid * 4) = *(const float4*)(vattn + tid * 4);
  }
  __syncthreads();
  float s = 0.f;
  const float* ep = encP + (size_t)tid * ADIM;
#pragma unroll 4
  for (int a = 0; a < ADIM; a += 4) {
    float4 e4 = *(const float4*)(ep + a);
    s += vv[a] * tanh_fast(e4.x + dp[a]);
    s += vv[a + 1] * tanh_fast(e4.y + dp[a + 1]);
    s += vv[a + 2] * tanh_fast(e4.z + dp[a + 2]);
    s += vv[a + 3] * tanh_fast(e4.w + dp[a + 3]);
  }
  float m = s;
#pragma unroll
  for (int off = 32; off; off >>= 1) m = fmaxf(m, __shfl_xor(m, off));
  if ((tid & 63) == 0) red[tid >> 6] = m;
  __syncthreads();
  m = fmaxf(fmaxf(red[0], red[1]), fmaxf(red[2], red[3]));
  float p = __expf(s - m);
  pl[tid] = p;
  float sum = p;
#pragma unroll
  for (int off = 32; off; off >>= 1) sum += __shfl_xor(sum, off);
  if ((tid & 63) == 0) red[4 + (tid >> 6)] = sum;
  __syncthreads();
  float inv = 1.f / (red[4] + red[5] + red[6] + red[7]);
  float a0 = 0.f, a1 = 0.f;
  for (int e = 0; e < TEnc; ++e) {
    float pe = pl[e];
    a0 += pe * encH[(size_t)e * HID + tid];
    a1 += pe * encH[(size_t)e * HID + tid + 256];
  }
  concatbf[(size_t)t * 2 * HID + tid] = f2bf(a0 * inv);
  concatbf[(size_t)t * 2 * HID + tid + 256] = f2bf(a1 * inv);
}

extern "C" void kernel_launch(void* const* d_in, const int* in_sizes, int n_in,
                              void* d_out, int out_size, void* d_ws, size_t ws_size,
                              hipStream_t stream) {
  const float* x = (const float*)d_in[0];
  const float* y = (const float*)d_in[1];
  const float* Wi_e = (const float*)d_in[2];
  const float* bi_e = (const float*)d_in[4];
  const float* bh_e = (const float*)d_in[5];
  const float* Wi_d = (const float*)d_in[6];
  const float* Wh_d = (const float*)d_in[7];
  const float* bi_d = (const float*)d_in[8];
  const float* bh_d = (const float*)d_in[9];
  const float* Wh_attn = (const float*)d_in[10];
  const float* Ws_attn = (const float*)d_in[11];
  const float* b_attn = (const float*)d_in[12];
  const float* v_attn = (const float*)d_in[13];
  const float* W1 = (const float*)d_in[14];
  const float* b1 = (const float*)d_in[15];
  const float* W2 = (const float*)d_in[16];
  const float* b2 = (const float*)d_in[17];
  float* out = (float*)d_out;

  char* ws = (char*)d_ws;
  size_t off = 0;
  auto alloc = [&](size_t bytes) {
    char* p = ws + off;
    off += (bytes + 255) & ~(size_t)255;
    return p;
  };
  const size_t hxA_bytes = 2 * 512 * 128;   // line-padded atomic mailbox (128KB)
  const size_t hxS_bytes = 2 * 256 * 8;     // sys mirror (4KB)
  char* ctrl = alloc(hxA_bytes + hxS_bytes + 256);
  unsigned* hxA = (unsigned*)ctrl;
  unsigned long long* hxS = (unsigned long long*)(ctrl + hxA_bytes);
  unsigned* cnt = (unsigned*)(ctrl + hxA_bytes + hxS_bytes);   // 16 words
  unsigned* winner = cnt + 16;
  unsigned short* Xbf = (unsigned short*)alloc((size_t)TEnc * HID * 2);
  unsigned short* Ybf = (unsigned short*)alloc((size_t)TDec * HID * 2);
  float* giY = (float*)alloc((size_t)TDec * THREE_H * 4);
  float* encH = (float*)alloc((size_t)TEnc * HID * 4);
  unsigned short* encHbf = (unsigned short*)alloc((size_t)TEnc * HID * 2);
  float* encP = (float*)alloc((size_t)TEnc * ADIM * 4);
  float* decP = (float*)alloc((size_t)TDec * ADIM * 4);
  unsigned short* decSbf = (unsigned short*)alloc((size_t)TDec * HID * 2);
  unsigned short* concatbf = (unsigned short*)alloc((size_t)TDec * 2 * HID * 2);
  unsigned short* out1bf = (unsigned short*)alloc((size_t)TDec * 20000 * 2);

  hipMemsetAsync(ctrl, 0, hxA_bytes + hxS_bytes + 256, stream);

  auto* g32 = gemm_bt<32, 128>;
  auto* g80 = gemm_bt<80, 128>;
  auto* g64 = gemm_bt<64, 160>;
  const int smem32 = (128 + 32) * 128 * 2 * 2;      // 81920
  const int smem80 = (128 + 80) * 128 * 2 * 2;      // 106496
  const int smem64 = (128 + 64) * 160 * 2 * 2;      // 122880
  const int smemEnc = (128 + 96) * 128 * 2 * 2;     // 114688
  const int smemScan = 100608;                      // forces 1 WG/CU for election
  hipFuncSetAttribute((const void*)g32, hipFuncAttributeMaxDynamicSharedMemorySize, smem32);
  hipFuncSetAttribute((const void*)g80, hipFuncAttributeMaxDynamicSharedMemorySize, smem80);
  hipFuncSetAttribute((const void*)g64, hipFuncAttributeMaxDynamicSharedMemorySize, smem64);
  hipFuncSetAttribute((const void*)gemm_enc, hipFuncAttributeMaxDynamicSharedMemorySize, smemEnc);
  hipFuncSetAttribute((const void*)gru_scan_xcd, hipFuncAttributeMaxDynamicSharedMemorySize, smemScan);

  cvt_xy<<<(TEnc + TDec) * HID / 1024, 256, 0, stream>>>(x, y, Xbf, Ybf);
  // encoder GEMM + fused gates
  gemm_enc<<<dim3(2, 16), 256, smemEnc, stream>>>(Xbf, Wi_e, bi_e, bh_e, encH, encHbf);
  // encP = encH @ Wh_attn^T
  g32<<<dim3(2, 8), 256, smem32, stream>>>(encHbf, Wh_attn, nullptr, encP, nullptr, 256, 256, 512);
  // giY = Ybf @ Wi_d^T + bi_d
  g32<<<dim3(1, 48), 256, smem32, stream>>>(Ybf, Wi_d, bi_d, giY, nullptr, 128, 1536, 512);
  // sequential decoder: single-XCD L2-atomic scan (sys-scope fallback inside)
  gru_scan_xcd<<<256, 256, smemScan, stream>>>(Wh_d, bh_d, giY, encH + 255 * HID,
                                               hxA, hxS, cnt, winner, decSbf, concatbf);
  // decP = decS @ Ws_attn^T + b_attn
  g32<<<dim3(1, 8), 256, smem32, stream>>>(decSbf, Ws_attn, b_attn, decP, nullptr, 128, 256, 512);
  attn_ctx<<<TDec, 256, 0, stream>>>(encP, decP, v_attn, encH, concatbf);
  // out1 = concat @ W1^T + b1 (store bf16)
  g80<<<dim3(1, 250), 256, smem80, stream>>>(concatbf, W1, b1, nullptr, out1bf, 128, 20000, 1024);
  // out = out1 @ W2^T + b2 (f32 B-stream, 800MB once)
  g64<<<dim3(1, 157), 256, smem64, stream>>>(out1bf, W2, b2, out, nullptr, 128, NVOC, 20000);
}

// Round 11
// 643.787 us; speedup vs baseline: 1.2519x; 1.2519x over previous
//
#include <hip/hip_runtime.h>
#include <stdint.h>

#define HID 512
#define THREE_H 1536
#define ADIM 256
#define NVOC 10000
#define TEnc 256
#define TDec 128

typedef float f32x4 __attribute__((ext_vector_type(4)));
typedef __bf16 bf16x8 __attribute__((ext_vector_type(8)));

__device__ __forceinline__ unsigned short f2bf(float f) {
  union { float f; unsigned u; } v; v.f = f;
  unsigned r = v.u + 0x7FFFu + ((v.u >> 16) & 1u);
  return (unsigned short)(r >> 16);
}
__device__ __forceinline__ float sigmoidf_(float x) { return 1.f / (1.f + __expf(-x)); }
__device__ __forceinline__ float tanh_fast(float x) {
  float ax = fabsf(x);
  float e = __expf(ax + ax);
  float t = 1.f - 2.f / (e + 1.f);
  return copysignf(t, x);
}

// Exchange ledger (measured):
//  r4: sc0-only LOADS never observe remote stores (stale L1) -> forbidden.
//  r6-r9: sys-scope (sc0 sc1) handoff = ~2.9us/step, decomposed as
//         store-VISIBILITY ~2.6us + load RTT ~0.2us; invariant to line
//         spreading (r8) and poller rate (r9); store COUNT matters (r7).
//  r10: no-sc1 atomics do NOT form a cross-WG meeting point (fast path 0%
//       success; 1.9GB poll fallback traffic). Falsified.
//  r11 BET: AGENT-scope atomic RMWs (the proven-correct election machinery,
//  m20) execute AT the device coherence point -> producer's exchange is
//  visible after a one-way trip, consumer's fetch_or reads the point
//  directly. Attacks the 2.6us visibility leg, not the 0.2us poll leg.

#define GLDS16(gp, lp)                                                                 \
  __builtin_amdgcn_global_load_lds((const __attribute__((address_space(1))) void*)(gp),\
                                   (__attribute__((address_space(3))) void*)(lp), 16, 0, 0)

// ---------------- fp32 -> bf16 convert (x and y fused) ----------------
__global__ void cvt_xy(const float* __restrict__ x, const float* __restrict__ y,
                       unsigned short* __restrict__ xb, unsigned short* __restrict__ yb) {
  int i = (blockIdx.x * blockDim.x + threadIdx.x) * 4;
  const float* src;
  unsigned short* dst;
  int j;
  if (i < TEnc * HID) { src = x; dst = xb; j = i; }
  else { src = y; dst = yb; j = i - TEnc * HID; }
  float4 v = *(const float4*)(src + j);
  ushort4 o;
  o.x = f2bf(v.x); o.y = f2bf(v.y); o.z = f2bf(v.z); o.w = f2bf(v.w);
  *(ushort4*)(dst + j) = o;
}

// ---------------- BT-GEMM: C[M,N] = A[M,K](bf16) * B[N,K]^T(f32->bf16) + bias ----------------
template <int BN, int BK>
__global__ __launch_bounds__(256, 1) void gemm_bt(
    const unsigned short* __restrict__ Abf, const float* __restrict__ B,
    const float* __restrict__ bias, float* __restrict__ C, unsigned short* __restrict__ Cbf,
    int M, int N, int K) {
  constexpr int NF = BN / 16;
  constexpr int B4 = BN * BK / 1024;
  constexpr int AG = BK / 16;
  constexpr int KK = BK / 32;
  extern __shared__ char smem[];
  unsigned short* Al0 = (unsigned short*)smem;
  unsigned short* Al1 = Al0 + 128 * BK;
  unsigned short* Bl0 = Al1 + 128 * BK;
  unsigned short* Bl1 = Bl0 + BN * BK;

  const int tid = threadIdx.x;
  const int lane = tid & 63;
  const int wid = tid >> 6;
  const int m0 = blockIdx.x * 128;
  const int n0 = blockIdx.y * BN;
  const int NT = K / BK;

  float4 breg[B4];
  f32x4 acc[2][NF];
#pragma unroll
  for (int i = 0; i < 2; ++i)
#pragma unroll
    for (int j = 0; j < NF; ++j) acc[i][j] = (f32x4){0.f, 0.f, 0.f, 0.f};

  auto stageA = [&](int t, unsigned short* dst) {
    const unsigned short* Ab = Abf + (size_t)m0 * K + (size_t)t * BK;
#pragma unroll
    for (int g = 0; g < AG; ++g) {
      int elem = g * 2048 + tid * 8;
      int arow = elem / BK;
      int acol = elem - arow * BK;
      GLDS16(Ab + (size_t)arow * K + acol, (char*)dst + g * 4096 + wid * 1024);
    }
  };
  auto loadB = [&](int t) {
    const float* Bb = B + (size_t)t * BK;
#pragma unroll
    for (int p = 0; p < B4; ++p) {
      int e = (p * 256 + tid) * 4;
      int brow = e / BK;
      int bcol = e - brow * BK;
      int grow = n0 + brow;
      if (grow > N - 1) grow = N - 1;
      breg[p] = *(const float4*)(Bb + (size_t)grow * K + bcol);
    }
  };
  auto writeB = [&](unsigned short* dst) {
#pragma unroll
    for (int p = 0; p < B4; ++p) {
      ushort4 o;
      o.x = f2bf(breg[p].x); o.y = f2bf(breg[p].y);
      o.z = f2bf(breg[p].z); o.w = f2bf(breg[p].w);
      *(ushort4*)((char*)dst + (p * 256 + tid) * 8) = o;
    }
  };

  stageA(0, Al0);
  loadB(0);
  for (int t = 0; t < NT; ++t) {
    unsigned short* Ac = (t & 1) ? Al1 : Al0;
    unsigned short* Bc = (t & 1) ? Bl1 : Bl0;
    asm volatile("s_waitcnt vmcnt(0)" ::: "memory");
    writeB(Bc);
    __syncthreads();
    if (t + 1 < NT) {
      stageA(t + 1, (t & 1) ? Al0 : Al1);
      loadB(t + 1);
    }
    const int r0 = lane & 15;
    const int kb = (lane >> 4) * 8;
#pragma unroll
    for (int kk = 0; kk < KK; ++kk) {
      int ko = kk * 32 + kb;
      bf16x8 a0 = *(const bf16x8*)(Ac + (wid * 32 + r0) * BK + ko);
      bf16x8 a1 = *(const bf16x8*)(Ac + (wid * 32 + 16 + r0) * BK + ko);
#pragma unroll
      for (int nf = 0; nf < NF; ++nf) {
        bf16x8 bb = *(const bf16x8*)(Bc + (nf * 16 + r0) * BK + ko);
        acc[0][nf] = __builtin_amdgcn_mfma_f32_16x16x32_bf16(a0, bb, acc[0][nf], 0, 0, 0);
        acc[1][nf] = __builtin_amdgcn_mfma_f32_16x16x32_bf16(a1, bb, acc[1][nf], 0, 0, 0);
      }
    }
  }
  const int cc = lane & 15;
  const int rq = (lane >> 4) * 4;
#pragma unroll
  for (int mi = 0; mi < 2; ++mi) {
    int row = m0 + wid * 32 + mi * 16 + rq;
#pragma unroll
    for (int nf = 0; nf < NF; ++nf) {
      int col = n0 + nf * 16 + cc;
      if (col < N) {
        float bv = bias ? bias[col] : 0.f;
#pragma unroll
        for (int j = 0; j < 4; ++j) {
          float v = acc[mi][nf][j] + bv;
          if (C) C[(size_t)(row + j) * N + col] = v;
          if (Cbf) Cbf[(size_t)(row + j) * N + col] = f2bf(v);
        }
      }
    }
  }
}

// ---------------- encoder GEMM with fused GRU gates (h_prev = 0) ----------------
__global__ __launch_bounds__(256, 1) void gemm_enc(
    const unsigned short* __restrict__ Abf, const float* __restrict__ Wi,
    const float* __restrict__ bi, const float* __restrict__ bh,
    float* __restrict__ encH, unsigned short* __restrict__ encHbf) {
  constexpr int BN = 96, BK = 128, NF = 6, B4 = 12, AG = 8, KK = 4, K = 512;
  extern __shared__ char smem[];
  unsigned short* Al0 = (unsigned short*)smem;
  unsigned short* Al1 = Al0 + 128 * BK;
  unsigned short* Bl0 = Al1 + 128 * BK;
  unsigned short* Bl1 = Bl0 + BN * BK;

  const int tid = threadIdx.x;
  const int lane = tid & 63;
  const int wid = tid >> 6;
  const int m0 = blockIdx.x * 128;
  const int n0g = blockIdx.y * 32;
  const int NT = K / BK;

  float4 breg[B4];
  f32x4 acc[2][NF];
#pragma unroll
  for (int i = 0; i < 2; ++i)
#pragma unroll
    for (int j = 0; j < NF; ++j) acc[i][j] = (f32x4){0.f, 0.f, 0.f, 0.f};

  auto stageA = [&](int t, unsigned short* dst) {
    const unsigned short* Ab = Abf + (size_t)m0 * K + (size_t)t * BK;
#pragma unroll
    for (int g = 0; g < AG; ++g) {
      int elem = g * 2048 + tid * 8;
      int arow = elem >> 7;
      int acol = elem & 127;
      GLDS16(Ab + (size_t)arow * K + acol, (char*)dst + g * 4096 + wid * 1024);
    }
  };
  auto loadB = [&](int t) {
    const float* Bb = Wi + (size_t)t * BK;
#pragma unroll
    for (int p = 0; p < B4; ++p) {
      int e = (p * 256 + tid) * 4;
      int brow = e >> 7;
      int bcol = e & 127;
      int grow = (brow >> 5) * HID + n0g + (brow & 31);
      breg[p] = *(const float4*)(Bb + (size_t)grow * K + bcol);
    }
  };
  auto writeB = [&](unsigned short* dst) {
#pragma unroll
    for (int p = 0; p < B4; ++p) {
      ushort4 o;
      o.x = f2bf(breg[p].x); o.y = f2bf(breg[p].y);
      o.z = f2bf(breg[p].z); o.w = f2bf(breg[p].w);
      *(ushort4*)((char*)dst + (p * 256 + tid) * 8) = o;
    }
  };

  stageA(0, Al0);
  loadB(0);
  for (int t = 0; t < NT; ++t) {
    unsigned short* Ac = (t & 1) ? Al1 : Al0;
    unsigned short* Bc = (t & 1) ? Bl1 : Bl0;
    asm volatile("s_waitcnt vmcnt(0)" ::: "memory");
    writeB(Bc);
    __syncthreads();
    if (t + 1 < NT) {
      stageA(t + 1, (t & 1) ? Al0 : Al1);
      loadB(t + 1);
    }
    const int r0 = lane & 15;
    const int kb = (lane >> 4) * 8;
#pragma unroll
    for (int kk = 0; kk < KK; ++kk) {
      int ko = kk * 32 + kb;
      bf16x8 a0 = *(const bf16x8*)(Ac + (wid * 32 + r0) * BK + ko);
      bf16x8 a1 = *(const bf16x8*)(Ac + (wid * 32 + 16 + r0) * BK + ko);
#pragma unroll
      for (int nf = 0; nf < NF; ++nf) {
        bf16x8 bb = *(const bf16x8*)(Bc + (nf * 16 + r0) * BK + ko);
        acc[0][nf] = __builtin_amdgcn_mfma_f32_16x16x32_bf16(a0, bb, acc[0][nf], 0, 0, 0);
        acc[1][nf] = __builtin_amdgcn_mfma_f32_16x16x32_bf16(a1, bb, acc[1][nf], 0, 0, 0);
      }
    }
  }
  const int cc = lane & 15;
  const int rq = (lane >> 4) * 4;
#pragma unroll
  for (int mi = 0; mi < 2; ++mi) {
    int row = m0 + wid * 32 + mi * 16 + rq;
#pragma unroll
    for (int nfj = 0; nfj < 2; ++nfj) {
      int j = n0g + nfj * 16 + cc;
      float br_ = bi[j] + bh[j];
      float bz_ = bi[HID + j] + bh[HID + j];
      float bin_ = bi[2 * HID + j];
      float bhn_ = bh[2 * HID + j];
#pragma unroll
      for (int jj = 0; jj < 4; ++jj) {
        float r = sigmoidf_(acc[mi][nfj][jj] + br_);
        float z = sigmoidf_(acc[mi][nfj + 2][jj] + bz_);
        float n = tanh_fast(acc[mi][nfj + 4][jj] + bin_ + r * bhn_);
        float h = (1.f - z) * n;
        encH[(size_t)(row + jj) * HID + j] = h;
        encHbf[(size_t)(row + jj) * HID + j] = f2bf(h);
      }
    }
  }
}

// ---------------- sequential GRU scan: 32 WGs, AGENT-atomic exchange ----------------
// r6 structure; exchange via device-scope atomic RMWs (proven-correct
// cross-XCD machinery, m20). Producer: atomic_exchange of (tag<<32 | 2x bf16)
// -- data lands AT the coherence point after a one-way trip (attacks the
// measured ~2.6us store-visibility leg). Consumer: atomic_fetch_or(p, 0)
// -- executes at the point, never stale. Words line-padded (1 per 128B);
// each thread polls a ROTATED word (tid+g*8)&255 so the 32 WGs don't RMW
// the same address simultaneously. Own-dim recurrence fp32 in wave3's hreg.
__global__ __launch_bounds__(256, 1) void gru_scan(
    const float* __restrict__ Whd, const float* __restrict__ bhd,
    const float* __restrict__ giY, const float* __restrict__ h0,
    unsigned long long* __restrict__ hx,
    unsigned short* __restrict__ decSbf, unsigned short* __restrict__ concatbf) {
  __shared__ float hl[548];   // word w -> slot w + ((w>>7)<<2); 544 used
  __shared__ float dots[48];
  const int tid = threadIdx.x;
  const int lane = tid & 63, wid = tid >> 6;
  const int g = blockIdx.x;

  const int row16 = lane & 15;
  const int q = lane >> 4;
  float4 wreg[32];
  {
    int wrow = (wid < 3) ? wid : 0;
    const float* wr = Whd + ((size_t)wrow * HID + (size_t)g * 16 + row16) * HID + q * 128;
#pragma unroll
    for (int i = 0; i < 32; ++i) wreg[i] = *(const float4*)(wr + i * 4);
  }
  float bhr = 0.f, bhz = 0.f, bhn = 0.f, hreg = 0.f;
  if (wid == 3 && lane < 16) {
    int jj = g * 16 + lane;
    bhr = bhd[jj]; bhz = bhd[HID + jj]; bhn = bhd[2 * HID + jj];
    hreg = h0[jj];
  }
  {
    int w0 = tid * 2, w1 = tid * 2 + 1;
    hl[w0 + ((w0 >> 7) << 2)] = h0[w0];
    hl[w1 + ((w1 >> 7) << 2)] = h0[w1];
  }
  __syncthreads();

  for (int t = 0; t < TDec; ++t) {
    float gir = 0.f, giz = 0.f, gin = 0.f;
    if (wid < 3) {
      const float4* hp = (const float4*)hl;
      const int hb = q * 33;
      float p0 = 0.f, p1 = 0.f, p2 = 0.f, p3 = 0.f;
#pragma unroll
      for (int i = 0; i < 32; i += 4) {
        float4 ha = hp[hb + i], hv = hp[hb + i + 1], hc = hp[hb + i + 2], hd = hp[hb + i + 3];
        float4 wa = wreg[i], wb = wreg[i + 1], wc = wreg[i + 2], wd = wreg[i + 3];
        p0 += wa.x * ha.x + wa.y * ha.y + wa.z * ha.z + wa.w * ha.w;
        p1 += wb.x * hv.x + wb.y * hv.y + wb.z * hv.z + wb.w * hv.w;
        p2 += wc.x * hc.x + wc.y * hc.y + wc.z * hc.z + wc.w * hc.w;
        p3 += wd.x * hd.x + wd.y * hd.y + wd.z * hd.z + wd.w * hd.w;
      }
      float p = (p0 + p1) + (p2 + p3);
      p += __shfl_xor(p, 16);
      p += __shfl_xor(p, 32);
      if (lane < 16) dots[wid * 16 + lane] = p;
    } else if (lane < 16) {
      int jj = g * 16 + lane;
      const float* gi = giY + (size_t)t * THREE_H;
      gir = gi[jj]; giz = gi[HID + jj]; gin = gi[2 * HID + jj];  // hidden under dots
    }
    __syncthreads();  // dots ready; hl(t) reads done
    unsigned long long* hxB = hx + (size_t)(t & 1) * 256 * 16;  // 16 u64 = 128B/word
    if (wid == 3 && lane < 16) {
      int jj = g * 16 + lane;
      float r = sigmoidf_(gir + dots[lane] + bhr);
      float z = sigmoidf_(giz + dots[16 + lane] + bhz);
      float n = tanh_fast(gin + r * (dots[32 + lane] + bhn));
      float hn = (1.f - z) * n + z * hreg;
      hreg = hn;
      unsigned short hb16 = f2bf(hn);
      unsigned short hb_up = (unsigned short)__shfl_xor((int)hb16, 1);
      if ((lane & 1) == 0) {
        unsigned long long w = ((unsigned long long)(unsigned)(t + 1) << 32) |
                               ((unsigned)hb_up << 16) | (unsigned)hb16;
        // AGENT-scope publish: executes at the device coherence point
        __hip_atomic_exchange(hxB + (size_t)(g * 8 + (lane >> 1)) * 16, w,
                              __ATOMIC_RELAXED, __HIP_MEMORY_SCOPE_AGENT);
      }
      decSbf[(size_t)t * HID + jj] = hb16;
      concatbf[(size_t)t * 2 * HID + HID + jj] = hb16;
    }
    if (t == TDec - 1) break;
    {
      // rotated word assignment: WG g's thread tid fetches word (tid+g*8)&255
      const int wsrc = (tid + g * 8) & 255;
      unsigned long long* p0 = hxB + (size_t)wsrc * 16;
      const unsigned tag = (unsigned)(t + 1);
      unsigned long long v;
      int guard = 0;
      for (;;) {
        v = __hip_atomic_fetch_or(p0, 0ull, __ATOMIC_RELAXED, __HIP_MEMORY_SCOPE_AGENT);
        if ((unsigned)(v >> 32) == tag || ++guard >= (1 << 20)) break;
        __builtin_amdgcn_s_sleep(1);
      }
      int d0 = 2 * wsrc, d1 = 2 * wsrc + 1;
      hl[d0 + ((d0 >> 7) << 2)] = __uint_as_float(((unsigned)v & 0xFFFFu) << 16);
      hl[d1 + ((d1 >> 7) << 2)] = __uint_as_float((((unsigned)v >> 16) & 0xFFFFu) << 16);
    }
    __syncthreads();  // hl(t+1) ready
  }
}

// ---------------- attention scores + softmax + context ----------------
__global__ __launch_bounds__(256) void attn_ctx(const float* __restrict__ encP,
                                                const float* __restrict__ decP,
                                                const float* __restrict__ vattn,
                                                const float* __restrict__ encH,
                                                unsigned short* __restrict__ concatbf) {
  __shared__ float dp[ADIM], vv[ADIM], pl[TEnc];
  __shared__ float red[8];
  const int t = blockIdx.x, tid = threadIdx.x;
  if (tid < 64) {
    *(float4*)(dp + tid * 4) = *(const float4*)(decP + (size_t)t * ADIM + tid * 4);
    *(float4*)(vv + tid * 4) = *(const float4*)(vattn + tid * 4);
  }
  __syncthreads();
  float s = 0.f;
  const float* ep = encP + (size_t)tid * ADIM;
#pragma unroll 4
  for (int a = 0; a < ADIM; a += 4) {
    float4 e4 = *(const float4*)(ep + a);
    s += vv[a] * tanh_fast(e4.x + dp[a]);
    s += vv[a + 1] * tanh_fast(e4.y + dp[a + 1]);
    s += vv[a + 2] * tanh_fast(e4.z + dp[a + 2]);
    s += vv[a + 3] * tanh_fast(e4.w + dp[a + 3]);
  }
  float m = s;
#pragma unroll
  for (int off = 32; off; off >>= 1) m = fmaxf(m, __shfl_xor(m, off));
  if ((tid & 63) == 0) red[tid >> 6] = m;
  __syncthreads();
  m = fmaxf(fmaxf(red[0], red[1]), fmaxf(red[2], red[3]));
  float p = __expf(s - m);
  pl[tid] = p;
  float sum = p;
#pragma unroll
  for (int off = 32; off; off >>= 1) sum += __shfl_xor(sum, off);
  if ((tid & 63) == 0) red[4 + (tid >> 6)] = sum;
  __syncthreads();
  float inv = 1.f / (red[4] + red[5] + red[6] + red[7]);
  float a0 = 0.f, a1 = 0.f;
  for (int e = 0; e < TEnc; ++e) {
    float pe = pl[e];
    a0 += pe * encH[(size_t)e * HID + tid];
    a1 += pe * encH[(size_t)e * HID + tid + 256];
  }
  concatbf[(size_t)t * 2 * HID + tid] = f2bf(a0 * inv);
  concatbf[(size_t)t * 2 * HID + tid + 256] = f2bf(a1 * inv);
}

extern "C" void kernel_launch(void* const* d_in, const int* in_sizes, int n_in,
                              void* d_out, int out_size, void* d_ws, size_t ws_size,
                              hipStream_t stream) {
  const float* x = (const float*)d_in[0];
  const float* y = (const float*)d_in[1];
  const float* Wi_e = (const float*)d_in[2];
  const float* bi_e = (const float*)d_in[4];
  const float* bh_e = (const float*)d_in[5];
  const float* Wi_d = (const float*)d_in[6];
  const float* Wh_d = (const float*)d_in[7];
  const float* bi_d = (const float*)d_in[8];
  const float* bh_d = (const float*)d_in[9];
  const float* Wh_attn = (const float*)d_in[10];
  const float* Ws_attn = (const float*)d_in[11];
  const float* b_attn = (const float*)d_in[12];
  const float* v_attn = (const float*)d_in[13];
  const float* W1 = (const float*)d_in[14];
  const float* b1 = (const float*)d_in[15];
  const float* W2 = (const float*)d_in[16];
  const float* b2 = (const float*)d_in[17];
  float* out = (float*)d_out;

  char* ws = (char*)d_ws;
  size_t off = 0;
  auto alloc = [&](size_t bytes) {
    char* p = ws + off;
    off += (bytes + 255) & ~(size_t)255;
    return p;
  };
  const size_t hx_bytes = 2 * 256 * 128;               // line-padded mailbox, 64KB
  char* ctrl = alloc(hx_bytes);
  unsigned long long* hx = (unsigned long long*)ctrl;
  unsigned short* Xbf = (unsigned short*)alloc((size_t)TEnc * HID * 2);
  unsigned short* Ybf = (unsigned short*)alloc((size_t)TDec * HID * 2);
  float* giY = (float*)alloc((size_t)TDec * THREE_H * 4);
  float* encH = (float*)alloc((size_t)TEnc * HID * 4);
  unsigned short* encHbf = (unsigned short*)alloc((size_t)TEnc * HID * 2);
  float* encP = (float*)alloc((size_t)TEnc * ADIM * 4);
  float* decP = (float*)alloc((size_t)TDec * ADIM * 4);
  unsigned short* decSbf = (unsigned short*)alloc((size_t)TDec * HID * 2);
  unsigned short* concatbf = (unsigned short*)alloc((size_t)TDec * 2 * HID * 2);
  unsigned short* out1bf = (unsigned short*)alloc((size_t)TDec * 20000 * 2);

  hipMemsetAsync(ctrl, 0, hx_bytes, stream);  // zero exchange tags

  auto* g32 = gemm_bt<32, 128>;
  auto* g80 = gemm_bt<80, 128>;
  auto* g64 = gemm_bt<64, 160>;
  const int smem32 = (128 + 32) * 128 * 2 * 2;      // 81920
  const int smem80 = (128 + 80) * 128 * 2 * 2;      // 106496
  const int smem64 = (128 + 64) * 160 * 2 * 2;      // 122880
  const int smemEnc = (128 + 96) * 128 * 2 * 2;     // 114688
  hipFuncSetAttribute((const void*)g32, hipFuncAttributeMaxDynamicSharedMemorySize, smem32);
  hipFuncSetAttribute((const void*)g80, hipFuncAttributeMaxDynamicSharedMemorySize, smem80);
  hipFuncSetAttribute((const void*)g64, hipFuncAttributeMaxDynamicSharedMemorySize, smem64);
  hipFuncSetAttribute((const void*)gemm_enc, hipFuncAttributeMaxDynamicSharedMemorySize, smemEnc);

  cvt_xy<<<(TEnc + TDec) * HID / 1024, 256, 0, stream>>>(x, y, Xbf, Ybf);
  // encoder GEMM + fused gates
  gemm_enc<<<dim3(2, 16), 256, smemEnc, stream>>>(Xbf, Wi_e, bi_e, bh_e, encH, encHbf);
  // encP = encH @ Wh_attn^T
  g32<<<dim3(2, 8), 256, smem32, stream>>>(encHbf, Wh_attn, nullptr, encP, nullptr, 256, 256, 512);
  // giY = Ybf @ Wi_d^T + bi_d
  g32<<<dim3(1, 48), 256, smem32, stream>>>(Ybf, Wi_d, bi_d, giY, nullptr, 128, 1536, 512);
  // sequential decoder: AGENT-atomic mailbox scan
  gru_scan<<<32, 256, 0, stream>>>(Wh_d, bh_d, giY, encH + 255 * HID, hx, decSbf, concatbf);
  // decP = decS @ Ws_attn^T + b_attn
  g32<<<dim3(1, 8), 256, smem32, stream>>>(decSbf, Ws_attn, b_attn, decP, nullptr, 128, 256, 512);
  attn_ctx<<<TDec, 256, 0, stream>>>(encP, decP, v_attn, encH, concatbf);
  // out1 = concat @ W1^T + b1 (store bf16)
  g80<<<dim3(1, 250), 256, smem80, stream>>>(concatbf, W1, b1, nullptr, out1bf, 128, 20000, 1024);
  // out = out1 @ W2^T + b2 (f32 B-stream, 800MB once)
  g64<<<dim3(1, 157), 256, smem64, stream>>>(out1bf, W2, b2, out, nullptr, 128, NVOC, 20000);
}